// Round 21
// baseline (152.379 us; speedup 1.0000x reference)
//
#include <hip/hip_runtime.h>

#define EPSC 1e-10f
#define BDIM 512
#define PDIM 1024
#define NDIM 1024
#define TDIM 32

typedef __attribute__((ext_vector_type(8))) short short8;
typedef __attribute__((ext_vector_type(4))) float f32x4;
typedef __attribute__((ext_vector_type(2))) float f32x2;
typedef __attribute__((ext_vector_type(2))) int int2v;

static __device__ __forceinline__ short f2bf(float f) {
  unsigned u = __float_as_uint(f);
  unsigned r = (u + 0x7fffu + ((u >> 16) & 1u)) >> 16;
  return (short)r;
}

// ---- VALU-pipe cross-lane reductions (DPP + permlane swaps, no DS ops) ----
template <int CTRL>
static __device__ __forceinline__ float dpp_add(float x) {
  int t = __builtin_amdgcn_update_dpp(0, __float_as_int(x), CTRL, 0xf, 0xf, true);
  return x + __int_as_float(t);
}
static __device__ __forceinline__ float sum16_all(float x) {
  x = dpp_add<0xB1>(x);    // quad_perm xor1
  x = dpp_add<0x4E>(x);    // quad_perm xor2
  x = dpp_add<0x141>(x);   // row_half_mirror
  x = dpp_add<0x140>(x);   // row_mirror
  return x;
}
static __device__ __forceinline__ float sum32_all(float x) {
  x = sum16_all(x);
  int2v r = __builtin_amdgcn_permlane16_swap(__float_as_int(x), __float_as_int(x), false, false);
  return __int_as_float(r[0]) + __int_as_float(r[1]);
}
static __device__ __forceinline__ float sum64_all(float x) {
  x = sum32_all(x);
  int2v r = __builtin_amdgcn_permlane32_swap(__float_as_int(x), __float_as_int(x), false, false);
  return __int_as_float(r[0]) + __int_as_float(r[1]);
}

// ---- fused conversions: blocks [0,256) = conv_x, [256,768) = conv_w ----
__global__ __launch_bounds__(256) void conv_kernel(
    const float* __restrict__ X, short* __restrict__ Xbf,
    const float* __restrict__ W1, const float* __restrict__ W2,
    short* __restrict__ T1, short* __restrict__ T2, float* __restrict__ accums)
{
  __shared__ float T[64][65];
  __shared__ float red[4];
  int tid = threadIdx.x;
  int bid = blockIdx.x;
  if (bid < 256) {
    size_t base = (size_t)bid * 2048 + (size_t)tid * 8;
    float4 v0 = *(const float4*)(X + base);
    float4 v1 = *(const float4*)(X + base + 4);
    short8 o;
    o[0] = f2bf(v0.x); o[1] = f2bf(v0.y); o[2] = f2bf(v0.z); o[3] = f2bf(v0.w);
    o[4] = f2bf(v1.x); o[5] = f2bf(v1.y); o[6] = f2bf(v1.z); o[7] = f2bf(v1.w);
    *(short8*)(Xbf + base) = o;
    return;
  }
  int wbid = bid - 256;
  int z = wbid >> 8;
  int rem = wbid & 255;
  int r0 = (rem >> 4) * 64;   // k rows
  int c0 = (rem & 15) * 64;   // n cols
  const float* src = z ? W2 : W1;
  short* dst = z ? T2 : T1;
  float wsq = 0.0f;
#pragma unroll
  for (int i = 0; i < 4; ++i) {
    int row = (tid >> 4) + i * 16;
    int col = (tid & 15) << 2;
    float4 v = *(const float4*)(src + (size_t)(r0 + row) * NDIM + c0 + col);
    T[row][col + 0] = v.x; T[row][col + 1] = v.y; T[row][col + 2] = v.z; T[row][col + 3] = v.w;
    wsq = fmaf(v.x, v.x, wsq); wsq = fmaf(v.y, v.y, wsq);
    wsq = fmaf(v.z, v.z, wsq); wsq = fmaf(v.w, v.w, wsq);
  }
  __syncthreads();
  int n = tid >> 2;
  int kb = (tid & 3) << 4;
  short8 o0, o1;
#pragma unroll
  for (int i = 0; i < 8; ++i) o0[i] = f2bf(T[kb + i][n]);
#pragma unroll
  for (int i = 0; i < 8; ++i) o1[i] = f2bf(T[kb + 8 + i][n]);
  short* dp = dst + (size_t)(c0 + n) * NDIM + r0 + kb;
  *(short8*)dp = o0;
  *(short8*)(dp + 8) = o1;
  wsq = sum64_all(wsq);
  if ((tid & 63) == 0) red[tid >> 6] = wsq;
  __syncthreads();
  if (tid == 0) atomicAdd(accums + 2, red[0] + red[1] + red[2] + red[3]);
}

// ---- gemm1: a = relu(x@w_enc + b); Abf (bf16), U[n][b] = (sig(a)-c0)/width ----
__global__ __launch_bounds__(512) void gemm1_mfma(
    const short* __restrict__ Xbf, const short* __restrict__ WT,
    const float* __restrict__ bias, const float* __restrict__ centers,
    short* __restrict__ Abf, float* __restrict__ U)
{
  __shared__ float red[4][64][9];   // stride 9: bank-conflict-free
  int tid = threadIdx.x;
  int lane = tid & 63, wid = tid >> 6;
  int ow = wid & 3, kz = wid >> 2;
  int q = lane >> 4, r16 = lane & 15;
  int bn = blockIdx.x * 32;
  int m = blockIdx.y * 64 + ow * 16 + r16;
  const short* ap  = Xbf + (size_t)m * NDIM + kz * 512 + q * 8;
  const short* b0p = WT + (size_t)(bn + r16) * NDIM + kz * 512 + q * 8;
  const short* b1p = b0p + 16 * NDIM;
  f32x4 acc0 = {0.f, 0.f, 0.f, 0.f};
  f32x4 acc1 = {0.f, 0.f, 0.f, 0.f};
#pragma unroll 4
  for (int k = 0; k < 512; k += 32) {
    short8 a  = *(const short8*)(ap + k);
    short8 b0 = *(const short8*)(b0p + k);
    short8 b1 = *(const short8*)(b1p + k);
    acc0 = __builtin_amdgcn_mfma_f32_16x16x32_bf16(a, b0, acc0, 0, 0, 0);
    acc1 = __builtin_amdgcn_mfma_f32_16x16x32_bf16(a, b1, acc1, 0, 0, 0);
  }
  if (kz) {
#pragma unroll
    for (int r = 0; r < 4; ++r) { red[ow][lane][r] = acc0[r]; red[ow][lane][r + 4] = acc1[r]; }
  }
  __syncthreads();
  if (!kz) {
#pragma unroll
    for (int r = 0; r < 4; ++r) { acc0[r] += red[ow][lane][r]; acc1[r] += red[ow][lane][r + 4]; }
    float c0v = centers[0];
    float invw = 1.0f / (centers[1] - centers[0]);
    int mrow = blockIdx.y * 64 + ow * 16 + (q << 2);
    int n0 = bn + r16;
    float bi0 = bias[n0], bi1 = bias[n0 + 16];
    float u0[4], u1[4];
#pragma unroll
    for (int r = 0; r < 4; ++r) {
      int mm = mrow + r;
      float a0 = fmaxf(acc0[r] + bi0, 0.0f);
      float a1 = fmaxf(acc1[r] + bi1, 0.0f);
      Abf[(size_t)mm * NDIM + n0]      = f2bf(a0);
      Abf[(size_t)mm * NDIM + n0 + 16] = f2bf(a1);
      u0[r] = (2.0f * __builtin_amdgcn_rcpf(1.0f + __expf(-a0)) - 1.0f - c0v) * invw;
      u1[r] = (2.0f * __builtin_amdgcn_rcpf(1.0f + __expf(-a1)) - 1.0f - c0v) * invw;
    }
    *(float4*)(U + (size_t)n0 * BDIM + mrow)          = *(float4*)u0;
    *(float4*)(U + (size_t)(n0 + 16) * BDIM + mrow)   = *(float4*)u1;
  }
}

// ---- gemm2 standalone: x_hat + recon-loss ----
__global__ __launch_bounds__(512) void gemm2_kernel(
    const short* __restrict__ Abf, const short* __restrict__ WdT,
    const float* __restrict__ b_dec, const float* __restrict__ X,
    float* __restrict__ out, float* __restrict__ accums)
{
  __shared__ float smem[2312];
  int tid = threadIdx.x;
  int bx = blockIdx.x;
  int lane = tid & 63, wid = tid >> 6;
  int ow = wid & 3, kz = wid >> 2;
  int q = lane >> 4, r16 = lane & 15;
  int bn = (bx & 31) * 32;
  int by = bx >> 5;
  int m = by * 64 + ow * 16 + r16;
  const short* ap  = Abf + (size_t)m * NDIM + kz * 512 + q * 8;
  const short* b0p = WdT + (size_t)(bn + r16) * NDIM + kz * 512 + q * 8;
  const short* b1p = b0p + 16 * NDIM;
  f32x4 acc0 = {0.f, 0.f, 0.f, 0.f};
  f32x4 acc1 = {0.f, 0.f, 0.f, 0.f};
#pragma unroll 4
  for (int k = 0; k < 512; k += 32) {
    short8 a  = *(const short8*)(ap + k);
    short8 b0 = *(const short8*)(b0p + k);
    short8 b1 = *(const short8*)(b1p + k);
    acc0 = __builtin_amdgcn_mfma_f32_16x16x32_bf16(a, b0, acc0, 0, 0, 0);
    acc1 = __builtin_amdgcn_mfma_f32_16x16x32_bf16(a, b1, acc1, 0, 0, 0);
  }
  float* rw = smem + ((ow * 64 + lane) * 9);
  if (kz) {
#pragma unroll
    for (int r = 0; r < 4; ++r) { rw[r] = acc0[r]; rw[r + 4] = acc1[r]; }
  }
  __syncthreads();
  float local = 0.0f;
  if (!kz) {
#pragma unroll
    for (int r = 0; r < 4; ++r) { acc0[r] += rw[r]; acc1[r] += rw[r + 4]; }
    int mrow = by * 64 + ow * 16 + (q << 2);
    int p0 = bn + r16;
    float bi0 = b_dec[p0], bi1 = b_dec[p0 + 16];
#pragma unroll
    for (int r = 0; r < 4; ++r) {
      int mm = mrow + r;
      float xh0 = acc0[r] + bi0;
      float xh1 = acc1[r] + bi1;
      out[(size_t)mm * PDIM + p0]      = xh0;
      out[(size_t)mm * PDIM + p0 + 16] = xh1;
      float d0 = xh0 - X[(size_t)mm * PDIM + p0];
      float d1 = xh1 - X[(size_t)mm * PDIM + p0 + 16];
      local = fmaf(d0, d0, local);
      local = fmaf(d1, d1, local);
    }
  }
  local = sum64_all(local);
  if ((tid & 63) == 0) smem[2304 + wid] = local;
  __syncthreads();
  if (tid == 0) {
    float s = 0.0f;
#pragma unroll
    for (int i = 0; i < 8; ++i) s += smem[2304 + i];
    atomicAdd(accums + 0, s);
  }
}

// ---- mle: TWO waves per neuron (occupancy fix: 2048 waves -> 2/SIMD) ----
// Wave pair (wid, wid^1) splits the 512-item batch (4 items/lane). Each wave:
// triangle + within-wave DPP reduce; pair-combine of colsum/S via 33-float
// LDS row (1 write + 1 read + 2 barriers per step). Both waves redundantly
// update identical theta copies, keeping pi-gathers intra-wave.
__global__ __launch_bounds__(512) void mle_kernel(
    const float* __restrict__ U, const float* __restrict__ thetas,
    float* __restrict__ out, float* __restrict__ ent_out, float* __restrict__ accums)
{
  __shared__ float comb[8][34];   // [wave][lane<32: colsum part, 32: S part]
  int tid = threadIdx.x;
  int bx = blockIdx.x;
  int wid = tid >> 6, lane = tid & 63;
  int pairw = wid >> 1;           // neuron index within block (0..3)
  int half = wid & 1;             // which 256-item half this wave owns
  int n = bx * 4 + pairw;
  const float* Un = U + (size_t)n * BDIM + (size_t)half * 256;
  float u_reg[4], f_reg[4];
  int j_reg[4];
#pragma unroll
  for (int i = 0; i < 4; ++i) {
    float u = Un[lane + i * 64];
    int j = (int)u;
    if (j > TDIM - 2) j = TDIM - 2;
    u_reg[i] = u;
    j_reg[i] = j;
    f_reg[i] = u - (float)j;
  }
  f32x2 cpair[9];
#pragma unroll
  for (int k2 = 0; k2 < 9; ++k2) {
    cpair[k2][0] = (float)(15 + 2 * k2);
    cpair[k2][1] = (float)(16 + 2 * k2);
  }
  const f32x2 f2one  = {1.0f, 1.0f};
  const f32x2 f2zero = {0.0f, 0.0f};
  float tv = thetas[(size_t)n * TDIM + (lane & 31)];
  int t = lane & 31;
  for (int step = 0; step < 15; ++step) {
    float e = __expf(tv - 1.0f);          // shift-invariant softmax
    float se = sum32_all(e);
    float pv = e * __builtin_amdgcn_rcpf(se);
    // batched gathers (4 items, one wait region)
    float pj[4], pj1[4];
#pragma unroll
    for (int i = 0; i < 4; ++i) {
      pj[i]  = __shfl(pv, j_reg[i]);      // j in [15,30] -> h0 lanes
      pj1[i] = __shfl(pv, j_reg[i] + 1);
    }
    float rr[4];
    float S = 0.0f;
#pragma unroll
    for (int i = 0; i < 4; ++i) {
      float p = fmaf(f_reg[i], pj1[i] - pj[i], pj[i]);
      rr[i] = __builtin_amdgcn_rcpf(p + EPSC);
      S = fmaf(p, rr[i], S);
    }
    // packed-f32 triangle accumulation (4 items)
    f32x2 cs2[9];
#pragma unroll
    for (int k2 = 0; k2 < 9; ++k2) cs2[k2] = f2zero;
#pragma unroll
    for (int i = 0; i < 4; ++i) {
      f32x2 u2 = {u_reg[i], u_reg[i]};
      f32x2 r2 = {rr[i], rr[i]};
#pragma unroll
      for (int k2 = 0; k2 < 9; ++k2) {
        f32x2 d = u2 - cpair[k2];
        f32x2 w = __builtin_elementwise_max(
            f2one - __builtin_elementwise_abs(d), f2zero);
        cs2[k2] = __builtin_elementwise_fma(w, r2, cs2[k2]);
      }
    }
    // within-wave reductions (VALU pipe)
    S = sum64_all(S);
    float colsum = 0.0f;
#pragma unroll
    for (int k = 0; k < 17; ++k) {
      float cv = sum64_all(cs2[k >> 1][k & 1]);
      colsum = (t == 15 + k) ? cv : colsum;
    }
    // pair combine: one LDS row per wave
    if (lane < 32) comb[wid][lane] = colsum;
    else if (lane == 32) comb[wid][32] = S;
    __syncthreads();
    float colsum_tot = colsum + ((lane < 32) ? comb[wid ^ 1][lane] : 0.0f);
    float S_tot = S + comb[wid ^ 1][32];
    __syncthreads();
    if (lane < 32) tv += 0.01f * pv * (colsum_tot - S_tot);
  }
  // entropy of final density estimate (pair-combined)
  float e = __expf(tv - 1.0f);
  float se = sum32_all(e);
  float pv = e * __builtin_amdgcn_rcpf(se);
  float pj[4], pj1[4];
#pragma unroll
  for (int i = 0; i < 4; ++i) {
    pj[i]  = __shfl(pv, j_reg[i]);
    pj1[i] = __shfl(pv, j_reg[i] + 1);
  }
  float ent_local = 0.0f;
#pragma unroll
  for (int i = 0; i < 4; ++i) {
    float p = fmaf(f_reg[i], pj1[i] - pj[i], pj[i]);
    ent_local = fmaf(p, __logf(p + EPSC), ent_local);
  }
  float E = sum64_all(ent_local);
  if (lane == 32) comb[wid][32] = E;
  __syncthreads();
  E += comb[wid ^ 1][32];
  if (half == 0 && lane == 0) {
    float entn = -E;
    ent_out[n] = entn;
    atomicAdd(accums + 1, entn);
  }
  // ---- finalize: last of 256 mle blocks computes total_loss ----
  __syncthreads();
  if (tid == 0) {
    __threadfence();
    float old = atomicAdd(accums + 3, 1.0f);
    if (old == 255.0f) {
      float recon = atomicAdd(accums + 0, 0.0f);
      float ent   = atomicAdd(accums + 1, 0.0f);
      float wsq   = atomicAdd(accums + 2, 0.0f);
      out[(size_t)BDIM * PDIM + NDIM] =
          recon * (0.5f / (float)BDIM) + 0.01f * ent + 0.00025f * wsq;
    }
  }
}

extern "C" void kernel_launch(void* const* d_in, const int* in_sizes, int n_in,
                              void* d_out, int out_size, void* d_ws, size_t ws_size,
                              hipStream_t stream) {
  (void)in_sizes; (void)n_in; (void)out_size; (void)ws_size;
  const float* x       = (const float*)d_in[0];
  const float* w_enc   = (const float*)d_in[1];
  const float* b_enc   = (const float*)d_in[2];
  const float* w_dec   = (const float*)d_in[3];
  const float* b_dec   = (const float*)d_in[4];
  const float* thetas  = (const float*)d_in[5];
  const float* centers = (const float*)d_in[6];
  float* out = (float*)d_out;

  char* ws = (char*)d_ws;
  short* Xbf    = (short*)(ws);                 // 1 MB
  short* WT     = (short*)(ws + (1 << 20));     // 2 MB (w_enc^T bf16, [n][k])
  short* WdT    = (short*)(ws + (3 << 20));     // 2 MB (w_dec^T bf16, [p][n])
  short* Abf    = (short*)(ws + (5 << 20));     // 1 MB
  float* accums = (float*)(ws + (6 << 20));     // 16 B: recon, ent, wsq, counter
  float* U      = (float*)(ws + (7 << 20));     // 2 MB ([n][b])
  float* ent_out = out + (size_t)BDIM * PDIM;

  hipMemsetAsync(accums, 0, 16, stream);
  hipLaunchKernelGGL(conv_kernel, dim3(768), dim3(256), 0, stream,
                     x, Xbf, w_enc, w_dec, WT, WdT, accums);
  hipLaunchKernelGGL(gemm1_mfma, dim3(32, 8), dim3(512), 0, stream,
                     Xbf, WT, b_enc, centers, Abf, U);
  hipLaunchKernelGGL(gemm2_kernel, dim3(256), dim3(512), 0, stream,
                     Abf, WdT, b_dec, x, out, accums);
  hipLaunchKernelGGL(mle_kernel, dim3(256), dim3(512), 0, stream,
                     U, thetas, out, ent_out, accums);
}

// Round 22
// 138.575 us; speedup vs baseline: 1.0996x; 1.0996x over previous
//
#include <hip/hip_runtime.h>

#define EPSC 1e-10f
#define BDIM 512
#define PDIM 1024
#define NDIM 1024
#define TDIM 32

typedef __attribute__((ext_vector_type(8))) short short8;
typedef __attribute__((ext_vector_type(4))) float f32x4;
typedef __attribute__((ext_vector_type(2))) float f32x2;
typedef __attribute__((ext_vector_type(2))) int int2v;

static __device__ __forceinline__ short f2bf(float f) {
  unsigned u = __float_as_uint(f);
  unsigned r = (u + 0x7fffu + ((u >> 16) & 1u)) >> 16;
  return (short)r;
}

// ---- VALU-pipe cross-lane reductions (DPP + permlane swaps, no DS ops) ----
template <int CTRL>
static __device__ __forceinline__ float dpp_add(float x) {
  int t = __builtin_amdgcn_update_dpp(0, __float_as_int(x), CTRL, 0xf, 0xf, true);
  return x + __int_as_float(t);
}
static __device__ __forceinline__ float sum16_all(float x) {
  x = dpp_add<0xB1>(x);    // quad_perm xor1
  x = dpp_add<0x4E>(x);    // quad_perm xor2
  x = dpp_add<0x141>(x);   // row_half_mirror
  x = dpp_add<0x140>(x);   // row_mirror
  return x;
}
static __device__ __forceinline__ float sum32_all(float x) {
  x = sum16_all(x);
  int2v r = __builtin_amdgcn_permlane16_swap(__float_as_int(x), __float_as_int(x), false, false);
  return __int_as_float(r[0]) + __int_as_float(r[1]);
}
static __device__ __forceinline__ float sum64_all(float x) {
  x = sum32_all(x);
  int2v r = __builtin_amdgcn_permlane32_swap(__float_as_int(x), __float_as_int(x), false, false);
  return __int_as_float(r[0]) + __int_as_float(r[1]);
}

// ---- fused conversions: blocks [0,256) = conv_x, [256,768) = conv_w ----
__global__ __launch_bounds__(256) void conv_kernel(
    const float* __restrict__ X, short* __restrict__ Xbf,
    const float* __restrict__ W1, const float* __restrict__ W2,
    short* __restrict__ T1, short* __restrict__ T2, float* __restrict__ accums)
{
  __shared__ float T[64][65];
  __shared__ float red[4];
  int tid = threadIdx.x;
  int bid = blockIdx.x;
  if (bid < 256) {
    size_t base = (size_t)bid * 2048 + (size_t)tid * 8;
    float4 v0 = *(const float4*)(X + base);
    float4 v1 = *(const float4*)(X + base + 4);
    short8 o;
    o[0] = f2bf(v0.x); o[1] = f2bf(v0.y); o[2] = f2bf(v0.z); o[3] = f2bf(v0.w);
    o[4] = f2bf(v1.x); o[5] = f2bf(v1.y); o[6] = f2bf(v1.z); o[7] = f2bf(v1.w);
    *(short8*)(Xbf + base) = o;
    return;
  }
  int wbid = bid - 256;
  int z = wbid >> 8;
  int rem = wbid & 255;
  int r0 = (rem >> 4) * 64;   // k rows
  int c0 = (rem & 15) * 64;   // n cols
  const float* src = z ? W2 : W1;
  short* dst = z ? T2 : T1;
  float wsq = 0.0f;
#pragma unroll
  for (int i = 0; i < 4; ++i) {
    int row = (tid >> 4) + i * 16;
    int col = (tid & 15) << 2;
    float4 v = *(const float4*)(src + (size_t)(r0 + row) * NDIM + c0 + col);
    T[row][col + 0] = v.x; T[row][col + 1] = v.y; T[row][col + 2] = v.z; T[row][col + 3] = v.w;
    wsq = fmaf(v.x, v.x, wsq); wsq = fmaf(v.y, v.y, wsq);
    wsq = fmaf(v.z, v.z, wsq); wsq = fmaf(v.w, v.w, wsq);
  }
  __syncthreads();
  int n = tid >> 2;
  int kb = (tid & 3) << 4;
  short8 o0, o1;
#pragma unroll
  for (int i = 0; i < 8; ++i) o0[i] = f2bf(T[kb + i][n]);
#pragma unroll
  for (int i = 0; i < 8; ++i) o1[i] = f2bf(T[kb + 8 + i][n]);
  short* dp = dst + (size_t)(c0 + n) * NDIM + r0 + kb;
  *(short8*)dp = o0;
  *(short8*)(dp + 8) = o1;
  wsq = sum64_all(wsq);
  if ((tid & 63) == 0) red[tid >> 6] = wsq;
  __syncthreads();
  if (tid == 0) atomicAdd(accums + 2, red[0] + red[1] + red[2] + red[3]);
}

// ---- gemm1: a = relu(x@w_enc + b); Abf (bf16), U[n][b] = (sig(a)-c0)/width ----
__global__ __launch_bounds__(512) void gemm1_mfma(
    const short* __restrict__ Xbf, const short* __restrict__ WT,
    const float* __restrict__ bias, const float* __restrict__ centers,
    short* __restrict__ Abf, float* __restrict__ U)
{
  __shared__ float red[4][64][9];   // stride 9: bank-conflict-free
  int tid = threadIdx.x;
  int lane = tid & 63, wid = tid >> 6;
  int ow = wid & 3, kz = wid >> 2;
  int q = lane >> 4, r16 = lane & 15;
  int bn = blockIdx.x * 32;
  int m = blockIdx.y * 64 + ow * 16 + r16;
  const short* ap  = Xbf + (size_t)m * NDIM + kz * 512 + q * 8;
  const short* b0p = WT + (size_t)(bn + r16) * NDIM + kz * 512 + q * 8;
  const short* b1p = b0p + 16 * NDIM;
  f32x4 acc0 = {0.f, 0.f, 0.f, 0.f};
  f32x4 acc1 = {0.f, 0.f, 0.f, 0.f};
#pragma unroll 4
  for (int k = 0; k < 512; k += 32) {
    short8 a  = *(const short8*)(ap + k);
    short8 b0 = *(const short8*)(b0p + k);
    short8 b1 = *(const short8*)(b1p + k);
    acc0 = __builtin_amdgcn_mfma_f32_16x16x32_bf16(a, b0, acc0, 0, 0, 0);
    acc1 = __builtin_amdgcn_mfma_f32_16x16x32_bf16(a, b1, acc1, 0, 0, 0);
  }
  if (kz) {
#pragma unroll
    for (int r = 0; r < 4; ++r) { red[ow][lane][r] = acc0[r]; red[ow][lane][r + 4] = acc1[r]; }
  }
  __syncthreads();
  if (!kz) {
#pragma unroll
    for (int r = 0; r < 4; ++r) { acc0[r] += red[ow][lane][r]; acc1[r] += red[ow][lane][r + 4]; }
    float c0v = centers[0];
    float invw = 1.0f / (centers[1] - centers[0]);
    int mrow = blockIdx.y * 64 + ow * 16 + (q << 2);
    int n0 = bn + r16;
    float bi0 = bias[n0], bi1 = bias[n0 + 16];
    float u0[4], u1[4];
#pragma unroll
    for (int r = 0; r < 4; ++r) {
      int mm = mrow + r;
      float a0 = fmaxf(acc0[r] + bi0, 0.0f);
      float a1 = fmaxf(acc1[r] + bi1, 0.0f);
      Abf[(size_t)mm * NDIM + n0]      = f2bf(a0);
      Abf[(size_t)mm * NDIM + n0 + 16] = f2bf(a1);
      u0[r] = (2.0f * __builtin_amdgcn_rcpf(1.0f + __expf(-a0)) - 1.0f - c0v) * invw;
      u1[r] = (2.0f * __builtin_amdgcn_rcpf(1.0f + __expf(-a1)) - 1.0f - c0v) * invw;
    }
    *(float4*)(U + (size_t)n0 * BDIM + mrow)          = *(float4*)u0;
    *(float4*)(U + (size_t)(n0 + 16) * BDIM + mrow)   = *(float4*)u1;
  }
}

// ---- fused3: blocks [0,256) = mle (dispatched FIRST -> co-residency with
// gemm2 blocks in each CU's second slot); [256,512) = gemm2.
// Both role bodies are verbatim the round-21 verified kernels.
// mle: VALU/DS pipes; gemm2: MFMA/VMEM pipes -> overlap (m114).
__global__ __launch_bounds__(512, 4) void fused3_kernel(
    const short* __restrict__ Abf, const short* __restrict__ WdT,
    const float* __restrict__ b_dec, const float* __restrict__ X,
    const float* __restrict__ U, const float* __restrict__ thetas,
    float* __restrict__ out, float* __restrict__ ent_out, float* __restrict__ accums)
{
  __shared__ float smem[2312];   // gemm2: red 4*64*9 + scalars; mle: comb 8x34
  int tid = threadIdx.x;
  int bx = blockIdx.x;
  if (bx < 256) {
    // ================= mle role (round-21 verified body) =================
    float (*comb)[34] = (float (*)[34])smem;
    int wid = tid >> 6, lane = tid & 63;
    int pairw = wid >> 1;
    int half = wid & 1;
    int n = bx * 4 + pairw;
    const float* Un = U + (size_t)n * BDIM + (size_t)half * 256;
    float u_reg[4], f_reg[4];
    int j_reg[4];
#pragma unroll
    for (int i = 0; i < 4; ++i) {
      float u = Un[lane + i * 64];
      int j = (int)u;
      if (j > TDIM - 2) j = TDIM - 2;
      u_reg[i] = u;
      j_reg[i] = j;
      f_reg[i] = u - (float)j;
    }
    f32x2 cpair[9];
#pragma unroll
    for (int k2 = 0; k2 < 9; ++k2) {
      cpair[k2][0] = (float)(15 + 2 * k2);
      cpair[k2][1] = (float)(16 + 2 * k2);
    }
    const f32x2 f2one  = {1.0f, 1.0f};
    const f32x2 f2zero = {0.0f, 0.0f};
    float tv = thetas[(size_t)n * TDIM + (lane & 31)];
    int t = lane & 31;
    for (int step = 0; step < 15; ++step) {
      float e = __expf(tv - 1.0f);          // shift-invariant softmax
      float se = sum32_all(e);
      float pv = e * __builtin_amdgcn_rcpf(se);
      float pj[4], pj1[4];
#pragma unroll
      for (int i = 0; i < 4; ++i) {
        pj[i]  = __shfl(pv, j_reg[i]);      // j in [15,30] -> h0 lanes
        pj1[i] = __shfl(pv, j_reg[i] + 1);
      }
      float rr[4];
      float S = 0.0f;
#pragma unroll
      for (int i = 0; i < 4; ++i) {
        float p = fmaf(f_reg[i], pj1[i] - pj[i], pj[i]);
        rr[i] = __builtin_amdgcn_rcpf(p + EPSC);
        S = fmaf(p, rr[i], S);
      }
      f32x2 cs2[9];
#pragma unroll
      for (int k2 = 0; k2 < 9; ++k2) cs2[k2] = f2zero;
#pragma unroll
      for (int i = 0; i < 4; ++i) {
        f32x2 u2 = {u_reg[i], u_reg[i]};
        f32x2 r2 = {rr[i], rr[i]};
#pragma unroll
        for (int k2 = 0; k2 < 9; ++k2) {
          f32x2 d = u2 - cpair[k2];
          f32x2 w = __builtin_elementwise_max(
              f2one - __builtin_elementwise_abs(d), f2zero);
          cs2[k2] = __builtin_elementwise_fma(w, r2, cs2[k2]);
        }
      }
      S = sum64_all(S);
      float colsum = 0.0f;
#pragma unroll
      for (int k = 0; k < 17; ++k) {
        float cv = sum64_all(cs2[k >> 1][k & 1]);
        colsum = (t == 15 + k) ? cv : colsum;
      }
      if (lane < 32) comb[wid][lane] = colsum;
      else if (lane == 32) comb[wid][32] = S;
      __syncthreads();
      float colsum_tot = colsum + ((lane < 32) ? comb[wid ^ 1][lane] : 0.0f);
      float S_tot = S + comb[wid ^ 1][32];
      __syncthreads();
      if (lane < 32) tv += 0.01f * pv * (colsum_tot - S_tot);
    }
    // entropy of final density estimate (pair-combined)
    float e = __expf(tv - 1.0f);
    float se = sum32_all(e);
    float pv = e * __builtin_amdgcn_rcpf(se);
    float pj[4], pj1[4];
#pragma unroll
    for (int i = 0; i < 4; ++i) {
      pj[i]  = __shfl(pv, j_reg[i]);
      pj1[i] = __shfl(pv, j_reg[i] + 1);
    }
    float ent_local = 0.0f;
#pragma unroll
    for (int i = 0; i < 4; ++i) {
      float p = fmaf(f_reg[i], pj1[i] - pj[i], pj[i]);
      ent_local = fmaf(p, __logf(p + EPSC), ent_local);
    }
    float E = sum64_all(ent_local);
    if (lane == 32) comb[wid][32] = E;
    __syncthreads();
    E += comb[wid ^ 1][32];
    if (half == 0 && lane == 0) {
      float entn = -E;
      ent_out[n] = entn;
      atomicAdd(accums + 1, entn);
    }
  } else {
    // ================= gemm2 role (round-21 verified body) =================
    int bxx = bx - 256;
    int lane = tid & 63, wid = tid >> 6;
    int ow = wid & 3, kz = wid >> 2;
    int q = lane >> 4, r16 = lane & 15;
    int bn = (bxx & 31) * 32;
    int by = bxx >> 5;
    int m = by * 64 + ow * 16 + r16;
    const short* ap  = Abf + (size_t)m * NDIM + kz * 512 + q * 8;
    const short* b0p = WdT + (size_t)(bn + r16) * NDIM + kz * 512 + q * 8;
    const short* b1p = b0p + 16 * NDIM;
    f32x4 acc0 = {0.f, 0.f, 0.f, 0.f};
    f32x4 acc1 = {0.f, 0.f, 0.f, 0.f};
#pragma unroll 4
    for (int k = 0; k < 512; k += 32) {
      short8 a  = *(const short8*)(ap + k);
      short8 b0 = *(const short8*)(b0p + k);
      short8 b1 = *(const short8*)(b1p + k);
      acc0 = __builtin_amdgcn_mfma_f32_16x16x32_bf16(a, b0, acc0, 0, 0, 0);
      acc1 = __builtin_amdgcn_mfma_f32_16x16x32_bf16(a, b1, acc1, 0, 0, 0);
    }
    float* rw = smem + ((ow * 64 + lane) * 9);
    if (kz) {
#pragma unroll
      for (int r = 0; r < 4; ++r) { rw[r] = acc0[r]; rw[r + 4] = acc1[r]; }
    }
    __syncthreads();
    float local = 0.0f;
    if (!kz) {
#pragma unroll
      for (int r = 0; r < 4; ++r) { acc0[r] += rw[r]; acc1[r] += rw[r + 4]; }
      int mrow = by * 64 + ow * 16 + (q << 2);
      int p0 = bn + r16;
      float bi0 = b_dec[p0], bi1 = b_dec[p0 + 16];
#pragma unroll
      for (int r = 0; r < 4; ++r) {
        int mm = mrow + r;
        float xh0 = acc0[r] + bi0;
        float xh1 = acc1[r] + bi1;
        out[(size_t)mm * PDIM + p0]      = xh0;
        out[(size_t)mm * PDIM + p0 + 16] = xh1;
        float d0 = xh0 - X[(size_t)mm * PDIM + p0];
        float d1 = xh1 - X[(size_t)mm * PDIM + p0 + 16];
        local = fmaf(d0, d0, local);
        local = fmaf(d1, d1, local);
      }
    }
    local = sum64_all(local);
    if ((tid & 63) == 0) smem[2304 + wid] = local;
    __syncthreads();
    if (tid == 0) {
      float s = 0.0f;
#pragma unroll
      for (int i = 0; i < 8; ++i) s += smem[2304 + i];
      atomicAdd(accums + 0, s);
    }
  }
  // ---- finalize: last of 512 blocks computes total_loss ----
  __syncthreads();
  if (tid == 0) {
    __threadfence();
    float old = atomicAdd(accums + 3, 1.0f);
    if (old == 511.0f) {
      float recon = atomicAdd(accums + 0, 0.0f);
      float ent   = atomicAdd(accums + 1, 0.0f);
      float wsq   = atomicAdd(accums + 2, 0.0f);
      out[(size_t)BDIM * PDIM + NDIM] =
          recon * (0.5f / (float)BDIM) + 0.01f * ent + 0.00025f * wsq;
    }
  }
}

extern "C" void kernel_launch(void* const* d_in, const int* in_sizes, int n_in,
                              void* d_out, int out_size, void* d_ws, size_t ws_size,
                              hipStream_t stream) {
  (void)in_sizes; (void)n_in; (void)out_size; (void)ws_size;
  const float* x       = (const float*)d_in[0];
  const float* w_enc   = (const float*)d_in[1];
  const float* b_enc   = (const float*)d_in[2];
  const float* w_dec   = (const float*)d_in[3];
  const float* b_dec   = (const float*)d_in[4];
  const float* thetas  = (const float*)d_in[5];
  const float* centers = (const float*)d_in[6];
  float* out = (float*)d_out;

  char* ws = (char*)d_ws;
  short* Xbf    = (short*)(ws);                 // 1 MB
  short* WT     = (short*)(ws + (1 << 20));     // 2 MB (w_enc^T bf16, [n][k])
  short* WdT    = (short*)(ws + (3 << 20));     // 2 MB (w_dec^T bf16, [p][n])
  short* Abf    = (short*)(ws + (5 << 20));     // 1 MB
  float* accums = (float*)(ws + (6 << 20));     // 16 B: recon, ent, wsq, counter
  float* U      = (float*)(ws + (7 << 20));     // 2 MB ([n][b])
  float* ent_out = out + (size_t)BDIM * PDIM;

  hipMemsetAsync(accums, 0, 16, stream);
  hipLaunchKernelGGL(conv_kernel, dim3(768), dim3(256), 0, stream,
                     x, Xbf, w_enc, w_dec, WT, WdT, accums);
  hipLaunchKernelGGL(gemm1_mfma, dim3(32, 8), dim3(512), 0, stream,
                     Xbf, WT, b_enc, centers, Abf, U);
  hipLaunchKernelGGL(fused3_kernel, dim3(512), dim3(512), 0, stream,
                     Abf, WdT, b_dec, x, U, thetas, out, ent_out, accums);
}